// Round 6
// baseline (589.845 us; speedup 1.0000x reference)
//
#include <hip/hip_runtime.h>
#include <hip/hip_cooperative_groups.h>
#include <math.h>
#include <limits.h>

namespace cg = cooperative_groups;

// Problem constants (match reference)
#define BD 4
#define ZD 40
#define YD 1024
#define XD 1024
#define BZYX 167772160   // BD*ZD*YD*XD

constexpr int BLOCK = 256;
constexpr int GRID_MAX = 1024;                 // 4 blocks/CU x 256 CU
constexpr unsigned SMALL_LOG = 19;             // 512k slots * 8B = 4 MB
constexpr unsigned SMASK = (1u << SMALL_LOG) - 1;
constexpr unsigned long long EMPTY64 = ~0ull;
constexpr int BMW4 = BZYX / 8 / 16;            // bitmap size in uvec4 (1,310,720)
constexpr int STW4 = (8 << SMALL_LOG) / 16;    // stab size in uvec4 (262,144)

typedef unsigned uvec4 __attribute__((ext_vector_type(4)));

__device__ __forceinline__ unsigned hash_mix(unsigned x) {
    x ^= x >> 16; x *= 0x7feb352dU;
    x ^= x >> 15; x *= 0x846ca68bU;
    x ^= x >> 16;
    return x;
}
__device__ __forceinline__ float smooth_l1(float d) {
    float ad = fabsf(d);
    return (ad < 1.0f) ? 0.5f * d * d : ad - 0.5f;
}
__device__ __forceinline__ float logaddexp0(float l) {
    return (l > 0.0f) ? (l + log1pf(expf(-l))) : log1pf(expf(l));
}

// Tiled bitmap: one 64B line = 8z x 8y x 8x block of cells (all dims %8==0).
// gid = line*512 + bit; bijective with the linear cell id space.
__device__ __forceinline__ unsigned cell_gid(int b, int z, int y, int x) {
    unsigned line = ((unsigned)(b * (ZD >> 3) + (z >> 3)) * (YD >> 3) + (y >> 3)) * (XD >> 3) + (x >> 3);
    unsigned bit  = ((unsigned)(z & 7) << 6) | ((unsigned)(y & 7) << 3) | (unsigned)(x & 7);
    return (line << 9) | bit;
}
__device__ __forceinline__ bool bm_test(const unsigned* __restrict__ bm, unsigned gid) {
    return (bm[gid >> 5] >> (gid & 31)) & 1u;
}

// R==1 match: 27 bit-tests (~2 cache lines in tiled layout), argmin dL1 with
// first-k tie-break via distance-class masks (k ascending = jnp.argmin order).
__device__ __forceinline__ bool match27(const unsigned* __restrict__ bm,
                                        int b, int z, int y, int x,
                                        int& sz, int& sy, int& sx) {
    const int zc0 = max(z - 1, 0), zc2 = min(z + 1, ZD - 1);
    const int yc0 = max(y - 1, 0), yc2 = min(y + 1, YD - 1);
    const int xc0 = max(x - 1, 0), xc2 = min(x + 1, XD - 1);
    const int zc[3] = {zc0, z, zc2};
    const int yc[3] = {yc0, y, yc2};
    const int xc[3] = {xc0, x, xc2};
    unsigned hm = 0;
#pragma unroll
    for (int a = 0; a < 3; ++a)
#pragma unroll
        for (int c = 0; c < 3; ++c)
#pragma unroll
            for (int d = 0; d < 3; ++d)
                hm |= ((unsigned)bm_test(bm, cell_gid(b, zc[a], yc[c], xc[d]))) << (a * 9 + c * 3 + d);
    constexpr unsigned M0 = 1u << 13;
    constexpr unsigned M1 = (1u << 4) | (1u << 10) | (1u << 12) | (1u << 14) | (1u << 16) | (1u << 22);
    constexpr unsigned M2 = (1u << 1) | (1u << 3) | (1u << 5) | (1u << 7) | (1u << 9) | (1u << 11) |
                            (1u << 15) | (1u << 17) | (1u << 19) | (1u << 21) | (1u << 23) | (1u << 25);
    int bk;
    if (hm & M0)      bk = 13;
    else if (hm & M1) bk = __ffs((int)(hm & M1)) - 1;
    else if (hm & M2) bk = __ffs((int)(hm & M2)) - 1;
    else if (hm)      bk = __ffs((int)hm) - 1;
    else return false;
    // select via cndmask chains (avoid runtime-indexed arrays -> scratch)
    const int ai = bk / 9, ci = (bk / 3) % 3, di = bk % 3;
    sz = (ai == 0) ? zc0 : ((ai == 1) ? z : zc2);
    sy = (ci == 0) ? yc0 : ((ci == 1) ? y : yc2);
    sx = (di == 0) ? xc0 : ((di == 1) ? x : xc2);
    return true;
}

__device__ bool matchR(const unsigned* __restrict__ bm, int R,
                       int b, int z, int y, int x, int& sz, int& sy, int& sx) {
    int bestd = INT_MAX; bool m = false;
    for (int dz = -R; dz <= R; ++dz) {
        const int zz = min(max(z + dz, 0), ZD - 1);
        const int adz = abs(dz);
        for (int dy = -R; dy <= R; ++dy) {
            const int yy = min(max(y + dy, 0), YD - 1);
            const int adzy = adz + abs(dy);
            for (int dx = -R; dx <= R; ++dx) {
                const int d = adzy + abs(dx);
                if (d >= bestd) continue;
                const int xx = min(max(x + dx, 0), XD - 1);
                if (bm_test(bm, cell_gid(b, zz, yy, xx))) {
                    bestd = d; m = true; sz = zz; sy = yy; sx = xx;
                }
            }
        }
    }
    return m;
}

__device__ __forceinline__ void stab_insert(unsigned long long* __restrict__ stab, unsigned gid) {
    const unsigned long long desired = ((unsigned long long)gid << 32) | 0xFFFFFFFFull;
    unsigned s = hash_mix(gid) & SMASK;
    while (true) {
        unsigned long long old = atomicCAS(&stab[s], EMPTY64, desired);
        if (old == EMPTY64 || (unsigned)(old >> 32) == gid) return;
        s = (s + 1) & SMASK;
    }
}
// Probe reads are plain: key/emptiness are immutable during the scan phase;
// only the low-32 row mutates (via atomicMin), which probes don't depend on.
__device__ __forceinline__ void stab_minrow(unsigned long long* __restrict__ stab,
                                            unsigned gid, unsigned row) {
    unsigned s = hash_mix(gid) & SMASK;
    while (true) {
        const unsigned long long e = stab[s];
        if (e == EMPTY64) return;
        if ((unsigned)(e >> 32) == gid) { atomicMin((unsigned*)&stab[s], row); return; }
        s = (s + 1) & SMASK;
    }
}
// Row read must be coherent (rows mutated by other XCDs) -> atomic read.
__device__ __forceinline__ unsigned stab_getrow(unsigned long long* __restrict__ stab, unsigned gid) {
    unsigned s = hash_mix(gid) & SMASK;
    while (true) {
        const unsigned long long e = atomicAdd(&stab[s], 0ull);
        if ((unsigned)(e >> 32) == gid) return (unsigned)e;
        s = (s + 1) & SMASK;
    }
}

// ---------------- Cooperative fused kernel ----------------

__global__ void __launch_bounds__(BLOCK, 4)
fused_all(const float4* __restrict__ pf, const float* __restrict__ occ,
          const int4* __restrict__ ri, const float* __restrict__ lf,
          const int4* __restrict__ li, const int* __restrict__ Rptr,
          int Nr, int Nl,
          unsigned* __restrict__ bm, unsigned long long* __restrict__ stab,
          int* __restrict__ mcell, double* __restrict__ partials,
          float* __restrict__ out) {
    cg::grid_group grid = cg::this_grid();
    const int T = (int)(gridDim.x * blockDim.x);
    const int t = (int)(blockIdx.x * blockDim.x + threadIdx.x);
    const bool regR = (Nr <= T);        // one radar point per thread, kept in regs
    const bool regL = (Nl <= 4 * T);    // <=4 lidar points per thread, kept in regs

    // Preload radar point (loads overlap the clear-phase stores).
    int4 rib = make_int4(0, 0, 0, 0);
    float4 p = make_float4(0.f, 0.f, 0.f, 0.f);
    float logit = 0.f;
    if (regR && t < Nr) { rib = ri[t]; p = pf[t]; logit = occ[t]; }

    // ---- phase 0: clear bitmap (0x00) + fill stab (0xFF), nt streaming ----
    {
        uvec4* bmv = (uvec4*)bm;
        const uvec4 zz = (uvec4)(0u);
        for (int k = t; k < BMW4; k += T) __builtin_nontemporal_store(zz, &bmv[k]);
        uvec4* stv = (uvec4*)stab;
        const uvec4 ff = (uvec4)(~0u);
        for (int k = t; k < STW4; k += T) __builtin_nontemporal_store(ff, &stv[k]);
    }
    __threadfence();
    grid.sync();

    // ---- phase 1: build bitmap (1 atomicOr per lidar point); cache gids in regs ----
    unsigned cl0 = ~0u, cl1 = ~0u, cl2 = ~0u, cl3 = ~0u;
    if (regL) {
        int j = t;
        if (j < Nl) { int4 v = li[j]; cl0 = cell_gid(v.x, v.y, v.z, v.w);
                      atomicOr(&bm[cl0 >> 5], 1u << (cl0 & 31)); j += T; }
        if (j < Nl) { int4 v = li[j]; cl1 = cell_gid(v.x, v.y, v.z, v.w);
                      atomicOr(&bm[cl1 >> 5], 1u << (cl1 & 31)); j += T; }
        if (j < Nl) { int4 v = li[j]; cl2 = cell_gid(v.x, v.y, v.z, v.w);
                      atomicOr(&bm[cl2 >> 5], 1u << (cl2 & 31)); j += T; }
        if (j < Nl) { int4 v = li[j]; cl3 = cell_gid(v.x, v.y, v.z, v.w);
                      atomicOr(&bm[cl3 >> 5], 1u << (cl3 & 31)); }
    } else {
        for (int j = t; j < Nl; j += T) {
            int4 v = li[j];
            const unsigned gid = cell_gid(v.x, v.y, v.z, v.w);
            atomicOr(&bm[gid >> 5], 1u << (gid & 31));
        }
    }
    __threadfence();
    grid.sync();

    // ---- phase 2: radar match + occ/cnt/off sums + stab insert ----
    const int R = *Rptr;
    double occ_s = 0.0, cnt_s = 0.0, off_s = 0.0, feat_s = 0.0;
    int mc_reg = -1; float pw_reg = 0.f;

    for (int i = t; i < Nr; i += T) {
        int b, z, y, x; float4 pp; float lg;
        if (regR) { b = rib.x; z = rib.y; y = rib.z; x = rib.w; pp = p; lg = logit; }
        else { int4 r2 = ri[i]; b = r2.x; z = r2.y; y = r2.z; x = r2.w; pp = pf[i]; lg = occ[i]; }

        int sz = 0, sy = 0, sx = 0;
        const bool matched = (R == 1) ? match27(bm, b, z, y, x, sz, sy, sx)
                                      : matchR(bm, R, b, z, y, x, sz, sy, sx);
        float m = 0.f;
        int mc = -1;
        if (matched) {
            m = 1.f; cnt_s += 1.0;
            off_s += (double)(smooth_l1(pp.x - (float)(sx - x)) +
                              smooth_l1(pp.y - (float)(sy - y)) +
                              smooth_l1(pp.z - (float)(sz - z)));
            const unsigned gid = cell_gid(b, sz, sy, sx);
            stab_insert(stab, gid);
            mc = (int)gid;
        }
        if (regR) { mc_reg = mc; pw_reg = pp.w; } else mcell[i] = mc;
        occ_s += (double)(logaddexp0(lg) - lg * m);
    }
    __threadfence();
    grid.sync();

    // ---- phase 3: lidar scan (min original row per selected cell) ----
    if (regL) {
        if (cl0 != ~0u) stab_minrow(stab, cl0, (unsigned)t);
        if (cl1 != ~0u) stab_minrow(stab, cl1, (unsigned)(t + T));
        if (cl2 != ~0u) stab_minrow(stab, cl2, (unsigned)(t + 2 * T));
        if (cl3 != ~0u) stab_minrow(stab, cl3, (unsigned)(t + 3 * T));
    } else {
        for (int j = t; j < Nl; j += T) {
            int4 v = li[j];
            stab_minrow(stab, cell_gid(v.x, v.y, v.z, v.w), (unsigned)j);
        }
    }
    __threadfence();
    grid.sync();

    // ---- phase 4: feature loss ----
    if (regR) {
        if (mc_reg >= 0) {
            const unsigned row = stab_getrow(stab, (unsigned)mc_reg);
            feat_s = (double)fabsf(pw_reg - lf[(size_t)row * 4 + 3]);
        }
    } else {
        for (int i = t; i < Nr; i += T) {
            const int mc = mcell[i];
            if (mc >= 0) {
                const unsigned row = stab_getrow(stab, (unsigned)mc);
                feat_s += (double)fabsf(pf[i].w - lf[(size_t)row * 4 + 3]);
            }
        }
    }

    // ---- block reduction of the 4 sums ----
    __shared__ double sh[4][BLOCK];
    const int tid = threadIdx.x;
    sh[0][tid] = occ_s; sh[1][tid] = cnt_s; sh[2][tid] = off_s; sh[3][tid] = feat_s;
    __syncthreads();
    for (int s2 = BLOCK / 2; s2 > 0; s2 >>= 1) {
        if (tid < s2) {
            sh[0][tid] += sh[0][tid + s2];
            sh[1][tid] += sh[1][tid + s2];
            sh[2][tid] += sh[2][tid + s2];
            sh[3][tid] += sh[3][tid + s2];
        }
        __syncthreads();
    }
    if (tid == 0) {
        partials[blockIdx.x * 4 + 0] = sh[0][0];
        partials[blockIdx.x * 4 + 1] = sh[1][0];
        partials[blockIdx.x * 4 + 2] = sh[2][0];
        partials[blockIdx.x * 4 + 3] = sh[3][0];
    }
    __threadfence();
    grid.sync();

    // ---- phase 5: final reduce (block 0) ----
    if (blockIdx.x == 0) {
        double a0 = 0, a1 = 0, a2 = 0, a3 = 0;
        for (int k = tid; k < (int)gridDim.x; k += BLOCK) {
            a0 += partials[k * 4 + 0];
            a1 += partials[k * 4 + 1];
            a2 += partials[k * 4 + 2];
            a3 += partials[k * 4 + 3];
        }
        __syncthreads();
        sh[0][tid] = a0; sh[1][tid] = a1; sh[2][tid] = a2; sh[3][tid] = a3;
        __syncthreads();
        for (int s2 = BLOCK / 2; s2 > 0; s2 >>= 1) {
            if (tid < s2) {
                sh[0][tid] += sh[0][tid + s2];
                sh[1][tid] += sh[1][tid + s2];
                sh[2][tid] += sh[2][tid + s2];
                sh[3][tid] += sh[3][tid + s2];
            }
            __syncthreads();
        }
        if (tid == 0) {
            const double occ_loss = sh[0][0] / (double)Nr;
            const double cnt = sh[1][0];
            const double off_loss = sh[2][0] / fmax(cnt * 3.0, 1.0);
            const double feat_loss = sh[3][0] / fmax(cnt, 1.0);
            out[0] = (float)(0.2 * occ_loss + 1.0 * off_loss + 1.0 * feat_loss);
        }
    }
}

// ---------------- Fallback multi-kernel pipeline (if coop launch fails) ----------------

__global__ void fb_clear(uvec4* __restrict__ bmv, uvec4* __restrict__ stv) {
    const uvec4 zz = (uvec4)(0u);
    const uvec4 ff = (uvec4)(~0u);
    const int stride = gridDim.x * blockDim.x;
    for (int k = blockIdx.x * blockDim.x + threadIdx.x; k < BMW4; k += stride)
        __builtin_nontemporal_store(zz, &bmv[k]);
    for (int k = blockIdx.x * blockDim.x + threadIdx.x; k < STW4; k += stride)
        __builtin_nontemporal_store(ff, &stv[k]);
}

__global__ void fb_build(const int4* __restrict__ li, int Nl,
                         unsigned* __restrict__ bm, unsigned* __restrict__ cells) {
    const int j = blockIdx.x * blockDim.x + threadIdx.x;
    if (j >= Nl) return;
    int4 v = li[j];
    const unsigned gid = cell_gid(v.x, v.y, v.z, v.w);
    cells[j] = gid;
    atomicOr(&bm[gid >> 5], 1u << (gid & 31));
}

__global__ void __launch_bounds__(BLOCK)
fb_match(const float4* __restrict__ pf, const float* __restrict__ occ,
         const int4* __restrict__ ri, const unsigned* __restrict__ bm,
         unsigned long long* __restrict__ stab, const int* __restrict__ Rptr,
         int Nr, int* __restrict__ mcell, double* __restrict__ partials) {
    const int R = *Rptr;
    const int i = blockIdx.x * BLOCK + threadIdx.x;
    double occ_s = 0.0, cnt_s = 0.0, off_s = 0.0;
    if (i < Nr) {
        int4 rib = ri[i];
        const int b = rib.x, z = rib.y, y = rib.z, x = rib.w;
        int sz = 0, sy = 0, sx = 0;
        const bool matched = (R == 1) ? match27(bm, b, z, y, x, sz, sy, sx)
                                      : matchR(bm, R, b, z, y, x, sz, sy, sx);
        float m = 0.f; int mc = -1;
        if (matched) {
            m = 1.f; cnt_s = 1.0;
            const float4 pp = pf[i];
            off_s = (double)(smooth_l1(pp.x - (float)(sx - x)) +
                             smooth_l1(pp.y - (float)(sy - y)) +
                             smooth_l1(pp.z - (float)(sz - z)));
            const unsigned gid = cell_gid(b, sz, sy, sx);
            stab_insert(stab, gid);
            mc = (int)gid;
        }
        mcell[i] = mc;
        const float lg = occ[i];
        occ_s = (double)(logaddexp0(lg) - lg * m);
    }
    __shared__ double sh[3][BLOCK];
    const int tid = threadIdx.x;
    sh[0][tid] = occ_s; sh[1][tid] = cnt_s; sh[2][tid] = off_s;
    __syncthreads();
    for (int s = BLOCK / 2; s > 0; s >>= 1) {
        if (tid < s) {
            sh[0][tid] += sh[0][tid + s];
            sh[1][tid] += sh[1][tid + s];
            sh[2][tid] += sh[2][tid + s];
        }
        __syncthreads();
    }
    if (tid == 0) {
        partials[blockIdx.x * 4 + 0] = sh[0][0];
        partials[blockIdx.x * 4 + 1] = sh[1][0];
        partials[blockIdx.x * 4 + 2] = sh[2][0];
        partials[blockIdx.x * 4 + 3] = 0.0;
    }
}

__global__ void fb_scan(const unsigned* __restrict__ cells, int Nl,
                        unsigned long long* __restrict__ stab) {
    const int j = blockIdx.x * blockDim.x + threadIdx.x;
    if (j >= Nl) return;
    stab_minrow(stab, cells[j], (unsigned)j);
}

__global__ void __launch_bounds__(BLOCK)
fb_feat(const float4* __restrict__ pf, const int* __restrict__ mcell,
        unsigned long long* __restrict__ stab, const float* __restrict__ lf,
        int Nr, double* __restrict__ fpart) {
    const int i = blockIdx.x * BLOCK + threadIdx.x;
    double fs = 0.0;
    if (i < Nr) {
        const int mc = mcell[i];
        if (mc >= 0) {
            const unsigned row = stab_getrow(stab, (unsigned)mc);
            fs = (double)fabsf(pf[i].w - lf[(size_t)row * 4 + 3]);
        }
    }
    __shared__ double sh[BLOCK];
    const int tid = threadIdx.x;
    sh[tid] = fs;
    __syncthreads();
    for (int s = BLOCK / 2; s > 0; s >>= 1) {
        if (tid < s) sh[tid] += sh[tid + s];
        __syncthreads();
    }
    if (tid == 0) fpart[blockIdx.x] = sh[0];
}

__global__ void fb_finalize(const double* __restrict__ partials,
                            const double* __restrict__ fpart, int nblk,
                            int Nr, float* __restrict__ out) {
    __shared__ double sh[4][BLOCK];
    const int tid = threadIdx.x;
    double a0 = 0, a1 = 0, a2 = 0, a3 = 0;
    for (int i = tid; i < nblk; i += BLOCK) {
        a0 += partials[i * 4 + 0];
        a1 += partials[i * 4 + 1];
        a2 += partials[i * 4 + 2];
        a3 += partials[i * 4 + 3] + fpart[i];
    }
    sh[0][tid] = a0; sh[1][tid] = a1; sh[2][tid] = a2; sh[3][tid] = a3;
    __syncthreads();
    for (int s = BLOCK / 2; s > 0; s >>= 1) {
        if (tid < s) {
            sh[0][tid] += sh[0][tid + s];
            sh[1][tid] += sh[1][tid + s];
            sh[2][tid] += sh[2][tid + s];
            sh[3][tid] += sh[3][tid + s];
        }
        __syncthreads();
    }
    if (tid == 0) {
        const double occ_loss = sh[0][0] / (double)Nr;
        const double cnt = sh[1][0];
        const double off_loss = sh[2][0] / fmax(cnt * 3.0, 1.0);
        const double feat_loss = sh[3][0] / fmax(cnt, 1.0);
        out[0] = (float)(0.2 * occ_loss + 1.0 * off_loss + 1.0 * feat_loss);
    }
}

extern "C" void kernel_launch(void* const* d_in, const int* in_sizes, int n_in,
                              void* d_out, int out_size, void* d_ws, size_t ws_size,
                              hipStream_t stream) {
    const float4* pf = (const float4*)d_in[0];   // (Nr,4)
    const float*  oc = (const float*)d_in[1];    // (Nr,1,1)
    const int4*   ri = (const int4*)d_in[2];     // (Nr,4)
    const float*  lf = (const float*)d_in[3];    // (Nl,4)
    const int4*   li = (const int4*)d_in[4];     // (Nl,4)
    const int*    Rp = (const int*)d_in[5];      // scalar (device)

    int Nr = in_sizes[0] / 4;
    int Nl = in_sizes[3] / 4;
    const int nblk  = (Nr + BLOCK - 1) / BLOCK;
    const int nblkL = (Nl + BLOCK - 1) / BLOCK;

    // Workspace layout
    size_t off = 0;
    auto alloc = [&](size_t n) { size_t o = off; off += (n + 255) & ~(size_t)255; return o; };
    char* ws = (char*)d_ws;
    unsigned*           bm    = (unsigned*)(ws + alloc((size_t)BZYX / 8 + 256));
    unsigned long long* stab  = (unsigned long long*)(ws + alloc((size_t)8 << SMALL_LOG));
    int*                mcell = (int*)(ws + alloc((size_t)Nr * 4));
    unsigned*           cells = (unsigned*)(ws + alloc((size_t)Nl * 4));
    const int pblk = (nblk > GRID_MAX ? nblk : GRID_MAX);
    double*             parts = (double*)(ws + alloc((size_t)pblk * 5 * sizeof(double)));
    double*             fpart = parts + (size_t)pblk * 4;

    // Cooperative fused launch
    int dev = 0;
    (void)hipGetDevice(&dev);
    int cus = 0;
    (void)hipDeviceGetAttribute(&cus, hipDeviceAttributeMultiprocessorCount, dev);
    int maxBpc = 0;
    (void)hipOccupancyMaxActiveBlocksPerMultiprocessor(&maxBpc, fused_all, BLOCK, 0);
    int grid = maxBpc * cus;
    if (grid > GRID_MAX) grid = GRID_MAX;

    hipError_t err = hipErrorUnknown;
    if (grid >= 1) {
        float* outp = (float*)d_out;
        void* args[] = {(void*)&pf, (void*)&oc, (void*)&ri, (void*)&lf, (void*)&li,
                        (void*)&Rp, (void*)&Nr, (void*)&Nl, (void*)&bm, (void*)&stab,
                        (void*)&mcell, (void*)&parts, (void*)&outp};
        err = hipLaunchCooperativeKernel((const void*)fused_all, dim3(grid), dim3(BLOCK),
                                         args, 0, stream);
    }
    if (err != hipSuccess) {
        // Fallback: 6-kernel pipeline (same tiled bitmap + stab logic)
        fb_clear<<<4096, BLOCK, 0, stream>>>((uvec4*)bm, (uvec4*)stab);
        fb_build<<<nblkL, BLOCK, 0, stream>>>(li, Nl, bm, cells);
        fb_match<<<nblk, BLOCK, 0, stream>>>(pf, oc, ri, bm, stab, Rp, Nr, mcell, parts);
        fb_scan<<<nblkL, BLOCK, 0, stream>>>(cells, Nl, stab);
        fb_feat<<<nblk, BLOCK, 0, stream>>>(pf, mcell, stab, lf, Nr, fpart);
        fb_finalize<<<1, BLOCK, 0, stream>>>(parts, fpart, nblk, Nr, (float*)d_out);
    }
}

// Round 7
// 128.486 us; speedup vs baseline: 4.5907x; 4.5907x over previous
//
#include <hip/hip_runtime.h>
#include <math.h>
#include <limits.h>

// Problem constants (match reference)
#define BD 4
#define ZD 40
#define YD 1024
#define XD 1024
#define BZYX 167772160   // BD*ZD*YD*XD

constexpr int BLOCK = 256;
constexpr unsigned SMALL_LOG = 18;              // 256k slots * 8B = 2 MB
constexpr unsigned SMASK = (1u << SMALL_LOG) - 1;
constexpr size_t BM_BYTES   = (size_t)BZYX / 8;          // 20,971,520
constexpr size_t STAB_BYTES = (size_t)8 << SMALL_LOG;    // 2,097,152

__device__ __forceinline__ unsigned hash_mix(unsigned x) {
    x ^= x >> 16; x *= 0x7feb352dU;
    x ^= x >> 15; x *= 0x846ca68bU;
    x ^= x >> 16;
    return x;
}
__device__ __forceinline__ float smooth_l1(float d) {
    float ad = fabsf(d);
    return (ad < 1.0f) ? 0.5f * d * d : ad - 0.5f;
}
__device__ __forceinline__ float logaddexp0(float l) {
    return (l > 0.0f) ? (l + log1pf(expf(-l))) : log1pf(expf(l));
}

// Tiled bitmap: one 64B cache line = 8z x 8y x 8x block (all dims %8==0).
__device__ __forceinline__ unsigned cell_gid(int b, int z, int y, int x) {
    unsigned line = ((unsigned)(b * (ZD >> 3) + (z >> 3)) * (YD >> 3) + (y >> 3)) * (XD >> 3) + (x >> 3);
    unsigned bit  = ((unsigned)(z & 7) << 6) | ((unsigned)(y & 7) << 3) | (unsigned)(x & 7);
    return (line << 9) | bit;
}
__device__ __forceinline__ bool bm_test(const unsigned* __restrict__ bm, unsigned gid) {
    return (bm[gid >> 5] >> (gid & 31)) & 1u;
}

// R==1 match: 27 bit-tests (~2 cache lines), argmin dL1 with first-k
// tie-break via distance-class masks (k ascending = jnp.argmin order).
__device__ __forceinline__ bool match27(const unsigned* __restrict__ bm,
                                        int b, int z, int y, int x,
                                        int& sz, int& sy, int& sx) {
    const int zc0 = max(z - 1, 0), zc2 = min(z + 1, ZD - 1);
    const int yc0 = max(y - 1, 0), yc2 = min(y + 1, YD - 1);
    const int xc0 = max(x - 1, 0), xc2 = min(x + 1, XD - 1);
    const int zc[3] = {zc0, z, zc2};
    const int yc[3] = {yc0, y, yc2};
    const int xc[3] = {xc0, x, xc2};
    unsigned hm = 0;
#pragma unroll
    for (int a = 0; a < 3; ++a)
#pragma unroll
        for (int c = 0; c < 3; ++c)
#pragma unroll
            for (int d = 0; d < 3; ++d)
                hm |= ((unsigned)bm_test(bm, cell_gid(b, zc[a], yc[c], xc[d]))) << (a * 9 + c * 3 + d);
    constexpr unsigned M0 = 1u << 13;
    constexpr unsigned M1 = (1u << 4) | (1u << 10) | (1u << 12) | (1u << 14) | (1u << 16) | (1u << 22);
    constexpr unsigned M2 = (1u << 1) | (1u << 3) | (1u << 5) | (1u << 7) | (1u << 9) | (1u << 11) |
                            (1u << 15) | (1u << 17) | (1u << 19) | (1u << 21) | (1u << 23) | (1u << 25);
    int bk;
    if (hm & M0)      bk = 13;
    else if (hm & M1) bk = __ffs((int)(hm & M1)) - 1;
    else if (hm & M2) bk = __ffs((int)(hm & M2)) - 1;
    else if (hm)      bk = __ffs((int)hm) - 1;
    else return false;
    const int ai = bk / 9, ci = (bk / 3) % 3, di = bk % 3;
    sz = (ai == 0) ? zc0 : ((ai == 1) ? z : zc2);
    sy = (ci == 0) ? yc0 : ((ci == 1) ? y : yc2);
    sx = (di == 0) ? xc0 : ((di == 1) ? x : xc2);
    return true;
}

__device__ bool matchR(const unsigned* __restrict__ bm, int R,
                       int b, int z, int y, int x, int& sz, int& sy, int& sx) {
    int bestd = INT_MAX; bool m = false;
    for (int dz = -R; dz <= R; ++dz) {
        const int zz = min(max(z + dz, 0), ZD - 1);
        const int adz = abs(dz);
        for (int dy = -R; dy <= R; ++dy) {
            const int yy = min(max(y + dy, 0), YD - 1);
            const int adzy = adz + abs(dy);
            for (int dx = -R; dx <= R; ++dx) {
                const int d = adzy + abs(dx);
                if (d >= bestd) continue;
                const int xx = min(max(x + dx, 0), XD - 1);
                if (bm_test(bm, cell_gid(b, zz, yy, xx))) {
                    bestd = d; m = true; sz = zz; sy = yy; sx = xx;
                }
            }
        }
    }
    return m;
}

// stab encoding (memset-0 friendly): entry 0 = empty; key = gid+1 in high 32;
// low 32 = ~row accumulated with atomicMax (max(~row) == min(row); 0 = none).
__device__ __forceinline__ void stab_insert(unsigned long long* stab, unsigned gid) {
    const unsigned long long desired = ((unsigned long long)(gid + 1) << 32);
    unsigned s = hash_mix(gid) & SMASK;
    while (true) {
        unsigned long long old = atomicCAS(&stab[s], 0ull, desired);
        if (old == 0ull || (unsigned)(old >> 32) == gid + 1) return;
        s = (s + 1) & SMASK;
    }
}
__device__ __forceinline__ void stab_minrow(unsigned long long* stab, unsigned gid, unsigned row) {
    unsigned s = hash_mix(gid) & SMASK;
    while (true) {
        const unsigned long long e = stab[s];      // key immutable during scan
        if (e == 0ull) return;                     // cell not selected
        if ((unsigned)(e >> 32) == gid + 1) {
            atomicMax((unsigned*)&stab[s], ~row);  // low half
            return;
        }
        s = (s + 1) & SMASK;
    }
}
__device__ __forceinline__ unsigned stab_getrow(const unsigned long long* stab, unsigned gid) {
    unsigned s = hash_mix(gid) & SMASK;
    while (true) {
        const unsigned long long e = stab[s];
        if ((unsigned)(e >> 32) == gid + 1) return ~((unsigned)e);
        s = (s + 1) & SMASK;
    }
}

// ---- kernel 2: bitmap build + compact cell ids ----
__global__ void k_build(const int4* __restrict__ li, int Nl,
                        unsigned* __restrict__ bm, unsigned* __restrict__ cells) {
    const int j = blockIdx.x * blockDim.x + threadIdx.x;
    if (j >= Nl) return;
    int4 v = li[j];  // [b,z,y,x]
    const unsigned gid = cell_gid(v.x, v.y, v.z, v.w);
    cells[j] = gid;
    atomicOr(&bm[gid >> 5], 1u << (gid & 31));
}

// ---- kernel 3: radar match + occ/cnt/off sums + stab insert ----
__global__ void __launch_bounds__(BLOCK)
k_match(const float4* __restrict__ pf, const float* __restrict__ occ,
        const int4* __restrict__ ri, const unsigned* __restrict__ bm,
        unsigned long long* __restrict__ stab, const int* __restrict__ Rptr,
        int Nr, int* __restrict__ mcell, double* __restrict__ partials) {
    const int R = *Rptr;
    double occ_s = 0.0, cnt_s = 0.0, off_s = 0.0;
    const int stride = gridDim.x * blockDim.x;
    for (int i = blockIdx.x * BLOCK + threadIdx.x; i < Nr; i += stride) {
        int4 rib = ri[i];
        const int b = rib.x, z = rib.y, y = rib.z, x = rib.w;
        int sz = 0, sy = 0, sx = 0;
        const bool matched = (R == 1) ? match27(bm, b, z, y, x, sz, sy, sx)
                                      : matchR(bm, R, b, z, y, x, sz, sy, sx);
        float m = 0.f; int mc = -1;
        if (matched) {
            m = 1.f; cnt_s += 1.0;
            const float4 pp = pf[i];
            off_s += (double)(smooth_l1(pp.x - (float)(sx - x)) +
                              smooth_l1(pp.y - (float)(sy - y)) +
                              smooth_l1(pp.z - (float)(sz - z)));
            const unsigned gid = cell_gid(b, sz, sy, sx);
            stab_insert(stab, gid);
            mc = (int)gid;
        }
        mcell[i] = mc;
        const float lg = occ[i];
        occ_s += (double)(logaddexp0(lg) - lg * m);
    }
    __shared__ double sh[3][BLOCK];
    const int tid = threadIdx.x;
    sh[0][tid] = occ_s; sh[1][tid] = cnt_s; sh[2][tid] = off_s;
    __syncthreads();
    for (int s = BLOCK / 2; s > 0; s >>= 1) {
        if (tid < s) {
            sh[0][tid] += sh[0][tid + s];
            sh[1][tid] += sh[1][tid + s];
            sh[2][tid] += sh[2][tid + s];
        }
        __syncthreads();
    }
    if (tid == 0) {
        partials[blockIdx.x * 4 + 0] = sh[0][0];
        partials[blockIdx.x * 4 + 1] = sh[1][0];
        partials[blockIdx.x * 4 + 2] = sh[2][0];
        partials[blockIdx.x * 4 + 3] = 0.0;
    }
}

// ---- kernel 4: lidar scan (min original row per selected cell) ----
__global__ void k_scan(const unsigned* __restrict__ cells, int Nl,
                       unsigned long long* __restrict__ stab) {
    const int j = blockIdx.x * blockDim.x + threadIdx.x;
    if (j >= Nl) return;
    stab_minrow(stab, cells[j], (unsigned)j);
}

// ---- kernel 5: feature loss + last-block finalize ----
__global__ void __launch_bounds__(BLOCK)
k_feat(const float4* __restrict__ pf, const int* __restrict__ mcell,
       const unsigned long long* __restrict__ stab, const float* __restrict__ lf,
       int Nr, double* __restrict__ fpart, const double* __restrict__ partials,
       unsigned* __restrict__ counter, int mblk, float* __restrict__ out) {
    double fs = 0.0;
    const int stride = gridDim.x * blockDim.x;
    for (int i = blockIdx.x * BLOCK + threadIdx.x; i < Nr; i += stride) {
        const int mc = mcell[i];
        if (mc >= 0) {
            const unsigned row = stab_getrow(stab, (unsigned)mc);
            fs += (double)fabsf(pf[i].w - lf[(size_t)row * 4 + 3]);
        }
    }
    __shared__ double sh[4][BLOCK];
    __shared__ bool isLast;
    const int tid = threadIdx.x;
    sh[0][tid] = fs;
    __syncthreads();
    for (int s = BLOCK / 2; s > 0; s >>= 1) {
        if (tid < s) sh[0][tid] += sh[0][tid + s];
        __syncthreads();
    }
    if (tid == 0) {
        fpart[blockIdx.x] = sh[0][0];
        __threadfence();
        const unsigned done = atomicAdd(counter, 1u);
        isLast = (done == gridDim.x - 1);
    }
    __syncthreads();
    if (!isLast) return;

    // Last block: final reduce of match partials + feat partials.
    double a0 = 0, a1 = 0, a2 = 0, a3 = 0;
    for (int k = tid; k < mblk; k += BLOCK) {
        a0 += partials[k * 4 + 0];
        a1 += partials[k * 4 + 1];
        a2 += partials[k * 4 + 2];
    }
    for (int k = tid; k < (int)gridDim.x; k += BLOCK) a3 += fpart[k];
    __syncthreads();
    sh[0][tid] = a0; sh[1][tid] = a1; sh[2][tid] = a2; sh[3][tid] = a3;
    __syncthreads();
    for (int s = BLOCK / 2; s > 0; s >>= 1) {
        if (tid < s) {
            sh[0][tid] += sh[0][tid + s];
            sh[1][tid] += sh[1][tid + s];
            sh[2][tid] += sh[2][tid + s];
            sh[3][tid] += sh[3][tid + s];
        }
        __syncthreads();
    }
    if (tid == 0) {
        const double occ_loss = sh[0][0] / (double)Nr;
        const double cnt = sh[1][0];
        const double off_loss = sh[2][0] / fmax(cnt * 3.0, 1.0);
        const double feat_loss = sh[3][0] / fmax(cnt, 1.0);
        out[0] = (float)(0.2 * occ_loss + 1.0 * off_loss + 1.0 * feat_loss);
    }
}

extern "C" void kernel_launch(void* const* d_in, const int* in_sizes, int n_in,
                              void* d_out, int out_size, void* d_ws, size_t ws_size,
                              hipStream_t stream) {
    const float4* pf = (const float4*)d_in[0];   // (Nr,4)
    const float*  oc = (const float*)d_in[1];    // (Nr,1,1)
    const int4*   ri = (const int4*)d_in[2];     // (Nr,4)
    const float*  lf = (const float*)d_in[3];    // (Nl,4)
    const int4*   li = (const int4*)d_in[4];     // (Nl,4)
    const int*    Rp = (const int*)d_in[5];      // scalar (device)

    const int Nr = in_sizes[0] / 4;
    const int Nl = in_sizes[3] / 4;
    const int nblkL = (Nl + BLOCK - 1) / BLOCK;          // 4096
    int nblk = (Nr + BLOCK - 1) / BLOCK;                 // 1024
    if (nblk > 2048) nblk = 2048;                        // grid-stride beyond

    // Workspace layout: [bm][stab][counter] is one contiguous memset-0 region.
    size_t off = 0;
    auto alloc = [&](size_t n) { size_t o = off; off += (n + 255) & ~(size_t)255; return o; };
    char* ws = (char*)d_ws;
    unsigned*           bm    = (unsigned*)(ws + alloc(BM_BYTES));
    unsigned long long* stab  = (unsigned long long*)(ws + alloc(STAB_BYTES));
    unsigned*           counter = (unsigned*)(ws + alloc(256));
    const size_t zeroBytes = off;                        // bm + stab + counter
    unsigned*           cells = (unsigned*)(ws + alloc((size_t)Nl * 4));
    int*                mcell = (int*)(ws + alloc((size_t)Nr * 4));
    double*             parts = (double*)(ws + alloc((size_t)nblk * 4 * sizeof(double)));
    double*             fpart = (double*)(ws + alloc((size_t)nblk * sizeof(double)));

    hipError_t e0 = hipMemsetAsync(ws, 0, zeroBytes, stream); (void)e0;

    k_build<<<nblkL, BLOCK, 0, stream>>>(li, Nl, bm, cells);
    k_match<<<nblk, BLOCK, 0, stream>>>(pf, oc, ri, bm, stab, Rp, Nr, mcell, parts);
    k_scan<<<nblkL, BLOCK, 0, stream>>>(cells, Nl, stab);
    k_feat<<<nblk, BLOCK, 0, stream>>>(pf, mcell, stab, lf, Nr, fpart, parts,
                                       counter, nblk, (float*)d_out);
}

// Round 8
// 127.922 us; speedup vs baseline: 4.6110x; 1.0044x over previous
//
#include <hip/hip_runtime.h>
#include <math.h>
#include <limits.h>

// Problem constants (match reference)
#define BD 4
#define ZD 40
#define YD 1024
#define XD 1024
#define BZYX 167772160   // BD*ZD*YD*XD

constexpr int BLOCK = 256;
constexpr unsigned SMALL_LOG = 18;              // 256k slots * 8B = 2 MB
constexpr unsigned SMASK = (1u << SMALL_LOG) - 1;
constexpr size_t BM_BYTES   = (size_t)BZYX / 8;          // 20,971,520
constexpr size_t STAB_BYTES = (size_t)8 << SMALL_LOG;    // 2,097,152

__device__ __forceinline__ unsigned hash_mix(unsigned x) {
    x ^= x >> 16; x *= 0x7feb352dU;
    x ^= x >> 15; x *= 0x846ca68bU;
    x ^= x >> 16;
    return x;
}
__device__ __forceinline__ float smooth_l1(float d) {
    float ad = fabsf(d);
    return (ad < 1.0f) ? 0.5f * d * d : ad - 0.5f;
}
__device__ __forceinline__ float logaddexp0(float l) {
    return (l > 0.0f) ? (l + log1pf(expf(-l))) : log1pf(expf(l));
}

// Tiled bitmap: one 64B cache line = 8z x 8y x 8x block (all dims %8==0).
__device__ __forceinline__ unsigned cell_gid(int b, int z, int y, int x) {
    unsigned line = ((unsigned)(b * (ZD >> 3) + (z >> 3)) * (YD >> 3) + (y >> 3)) * (XD >> 3) + (x >> 3);
    unsigned bit  = ((unsigned)(z & 7) << 6) | ((unsigned)(y & 7) << 3) | (unsigned)(x & 7);
    return (line << 9) | bit;
}
__device__ __forceinline__ bool bm_test(const unsigned* __restrict__ bm, unsigned gid) {
    return (bm[gid >> 5] >> (gid & 31)) & 1u;
}

// R==1 match: 27 bit-tests (~2 cache lines), argmin dL1 with first-k
// tie-break via distance-class masks (k ascending = jnp.argmin order).
__device__ __forceinline__ bool match27(const unsigned* __restrict__ bm,
                                        int b, int z, int y, int x,
                                        int& sz, int& sy, int& sx) {
    const int zc0 = max(z - 1, 0), zc2 = min(z + 1, ZD - 1);
    const int yc0 = max(y - 1, 0), yc2 = min(y + 1, YD - 1);
    const int xc0 = max(x - 1, 0), xc2 = min(x + 1, XD - 1);
    const int zc[3] = {zc0, z, zc2};
    const int yc[3] = {yc0, y, yc2};
    const int xc[3] = {xc0, x, xc2};
    unsigned hm = 0;
#pragma unroll
    for (int a = 0; a < 3; ++a)
#pragma unroll
        for (int c = 0; c < 3; ++c)
#pragma unroll
            for (int d = 0; d < 3; ++d)
                hm |= ((unsigned)bm_test(bm, cell_gid(b, zc[a], yc[c], xc[d]))) << (a * 9 + c * 3 + d);
    constexpr unsigned M0 = 1u << 13;
    constexpr unsigned M1 = (1u << 4) | (1u << 10) | (1u << 12) | (1u << 14) | (1u << 16) | (1u << 22);
    constexpr unsigned M2 = (1u << 1) | (1u << 3) | (1u << 5) | (1u << 7) | (1u << 9) | (1u << 11) |
                            (1u << 15) | (1u << 17) | (1u << 19) | (1u << 21) | (1u << 23) | (1u << 25);
    int bk;
    if (hm & M0)      bk = 13;
    else if (hm & M1) bk = __ffs((int)(hm & M1)) - 1;
    else if (hm & M2) bk = __ffs((int)(hm & M2)) - 1;
    else if (hm)      bk = __ffs((int)hm) - 1;
    else return false;
    const int ai = bk / 9, ci = (bk / 3) % 3, di = bk % 3;
    sz = (ai == 0) ? zc0 : ((ai == 1) ? z : zc2);
    sy = (ci == 0) ? yc0 : ((ci == 1) ? y : yc2);
    sx = (di == 0) ? xc0 : ((di == 1) ? x : xc2);
    return true;
}

__device__ bool matchR(const unsigned* __restrict__ bm, int R,
                       int b, int z, int y, int x, int& sz, int& sy, int& sx) {
    int bestd = INT_MAX; bool m = false;
    for (int dz = -R; dz <= R; ++dz) {
        const int zz = min(max(z + dz, 0), ZD - 1);
        const int adz = abs(dz);
        for (int dy = -R; dy <= R; ++dy) {
            const int yy = min(max(y + dy, 0), YD - 1);
            const int adzy = adz + abs(dy);
            for (int dx = -R; dx <= R; ++dx) {
                const int d = adzy + abs(dx);
                if (d >= bestd) continue;
                const int xx = min(max(x + dx, 0), XD - 1);
                if (bm_test(bm, cell_gid(b, zz, yy, xx))) {
                    bestd = d; m = true; sz = zz; sy = yy; sx = xx;
                }
            }
        }
    }
    return m;
}

// stab encoding (zero-init friendly): entry 0 = empty; key = gid+1 in high 32;
// low 32 = ~row accumulated with atomicMax (max(~row) == min(row); 0 = none).
__device__ __forceinline__ void stab_insert(unsigned long long* stab, unsigned gid) {
    const unsigned long long desired = ((unsigned long long)(gid + 1) << 32);
    unsigned s = hash_mix(gid) & SMASK;
    while (true) {
        unsigned long long old = atomicCAS(&stab[s], 0ull, desired);
        if (old == 0ull || (unsigned)(old >> 32) == gid + 1) return;
        s = (s + 1) & SMASK;
    }
}
__device__ __forceinline__ void stab_minrow(unsigned long long* stab, unsigned gid, unsigned row) {
    unsigned s = hash_mix(gid) & SMASK;
    while (true) {
        const unsigned long long e = stab[s];      // key immutable during scan
        if (e == 0ull) return;                     // cell not selected
        if ((unsigned)(e >> 32) == gid + 1) {
            atomicMax((unsigned*)&stab[s], ~row);  // low half
            return;
        }
        s = (s + 1) & SMASK;
    }
}
__device__ __forceinline__ unsigned stab_getrow(const unsigned long long* stab, unsigned gid) {
    unsigned s = hash_mix(gid) & SMASK;
    while (true) {
        const unsigned long long e = stab[s];
        if ((unsigned)(e >> 32) == gid + 1) return ~((unsigned)e);
        s = (s + 1) & SMASK;
    }
}

// ---- kernel 1: clear bm + stab + counter (plain stores -> lines stay in LLC) ----
__global__ void k_clear(uint2* __restrict__ wsv, int n2) {
    const uint2 z = make_uint2(0u, 0u);
    const int stride = gridDim.x * blockDim.x;
    for (int k = blockIdx.x * blockDim.x + threadIdx.x; k < n2; k += stride)
        wsv[k] = z;
}

// ---- kernel 2: bitmap build + compact cell ids ----
__global__ void k_build(const int4* __restrict__ li, int Nl,
                        unsigned* __restrict__ bm, unsigned* __restrict__ cells) {
    const int j = blockIdx.x * blockDim.x + threadIdx.x;
    if (j >= Nl) return;
    int4 v = li[j];  // [b,z,y,x]
    const unsigned gid = cell_gid(v.x, v.y, v.z, v.w);
    cells[j] = gid;
    atomicOr(&bm[gid >> 5], 1u << (gid & 31));
}

// ---- kernel 3: radar match + occ/cnt/off sums + stab insert ----
__global__ void __launch_bounds__(BLOCK)
k_match(const float4* __restrict__ pf, const float* __restrict__ occ,
        const int4* __restrict__ ri, const unsigned* __restrict__ bm,
        unsigned long long* __restrict__ stab, const int* __restrict__ Rptr,
        int Nr, int* __restrict__ mcell, double* __restrict__ partials) {
    const int R = *Rptr;
    double occ_s = 0.0, cnt_s = 0.0, off_s = 0.0;
    const int stride = gridDim.x * blockDim.x;
    for (int i = blockIdx.x * BLOCK + threadIdx.x; i < Nr; i += stride) {
        int4 rib = ri[i];
        const int b = rib.x, z = rib.y, y = rib.z, x = rib.w;
        int sz = 0, sy = 0, sx = 0;
        const bool matched = (R == 1) ? match27(bm, b, z, y, x, sz, sy, sx)
                                      : matchR(bm, R, b, z, y, x, sz, sy, sx);
        float m = 0.f; int mc = -1;
        if (matched) {
            m = 1.f; cnt_s += 1.0;
            const float4 pp = pf[i];
            off_s += (double)(smooth_l1(pp.x - (float)(sx - x)) +
                              smooth_l1(pp.y - (float)(sy - y)) +
                              smooth_l1(pp.z - (float)(sz - z)));
            const unsigned gid = cell_gid(b, sz, sy, sx);
            stab_insert(stab, gid);
            mc = (int)gid;
        }
        mcell[i] = mc;
        const float lg = occ[i];
        occ_s += (double)(logaddexp0(lg) - lg * m);
    }
    __shared__ double sh[3][BLOCK];
    const int tid = threadIdx.x;
    sh[0][tid] = occ_s; sh[1][tid] = cnt_s; sh[2][tid] = off_s;
    __syncthreads();
    for (int s = BLOCK / 2; s > 0; s >>= 1) {
        if (tid < s) {
            sh[0][tid] += sh[0][tid + s];
            sh[1][tid] += sh[1][tid + s];
            sh[2][tid] += sh[2][tid + s];
        }
        __syncthreads();
    }
    if (tid == 0) {
        partials[blockIdx.x * 4 + 0] = sh[0][0];
        partials[blockIdx.x * 4 + 1] = sh[1][0];
        partials[blockIdx.x * 4 + 2] = sh[2][0];
        partials[blockIdx.x * 4 + 3] = 0.0;
    }
}

// ---- kernel 4: lidar scan (min original row per selected cell) ----
__global__ void k_scan(const unsigned* __restrict__ cells, int Nl,
                       unsigned long long* __restrict__ stab) {
    const int j = blockIdx.x * blockDim.x + threadIdx.x;
    if (j >= Nl) return;
    stab_minrow(stab, cells[j], (unsigned)j);
}

// ---- kernel 5: feature loss + last-block finalize ----
__global__ void __launch_bounds__(BLOCK)
k_feat(const float* __restrict__ pfw, const int* __restrict__ mcell,
       const unsigned long long* __restrict__ stab, const float* __restrict__ lf,
       int Nr, double* __restrict__ fpart, const double* __restrict__ partials,
       unsigned* __restrict__ counter, int mblk, float* __restrict__ out) {
    double fs = 0.0;
    const int stride = gridDim.x * blockDim.x;
    for (int i = blockIdx.x * BLOCK + threadIdx.x; i < Nr; i += stride) {
        const int mc = mcell[i];
        if (mc >= 0) {
            const unsigned row = stab_getrow(stab, (unsigned)mc);
            fs += (double)fabsf(pfw[(size_t)i * 4 + 3] - lf[(size_t)row * 4 + 3]);
        }
    }
    __shared__ double sh[4][BLOCK];
    __shared__ bool isLast;
    const int tid = threadIdx.x;
    sh[0][tid] = fs;
    __syncthreads();
    for (int s = BLOCK / 2; s > 0; s >>= 1) {
        if (tid < s) sh[0][tid] += sh[0][tid + s];
        __syncthreads();
    }
    if (tid == 0) {
        fpart[blockIdx.x] = sh[0][0];
        __threadfence();
        const unsigned done = atomicAdd(counter, 1u);
        isLast = (done == gridDim.x - 1);
    }
    __syncthreads();
    if (!isLast) return;

    // Last block: final reduce of match partials + feat partials.
    double a0 = 0, a1 = 0, a2 = 0, a3 = 0;
    for (int k = tid; k < mblk; k += BLOCK) {
        a0 += partials[k * 4 + 0];
        a1 += partials[k * 4 + 1];
        a2 += partials[k * 4 + 2];
    }
    for (int k = tid; k < (int)gridDim.x; k += BLOCK) a3 += fpart[k];
    __syncthreads();
    sh[0][tid] = a0; sh[1][tid] = a1; sh[2][tid] = a2; sh[3][tid] = a3;
    __syncthreads();
    for (int s = BLOCK / 2; s > 0; s >>= 1) {
        if (tid < s) {
            sh[0][tid] += sh[0][tid + s];
            sh[1][tid] += sh[1][tid + s];
            sh[2][tid] += sh[2][tid + s];
            sh[3][tid] += sh[3][tid + s];
        }
        __syncthreads();
    }
    if (tid == 0) {
        const double occ_loss = sh[0][0] / (double)Nr;
        const double cnt = sh[1][0];
        const double off_loss = sh[2][0] / fmax(cnt * 3.0, 1.0);
        const double feat_loss = sh[3][0] / fmax(cnt, 1.0);
        out[0] = (float)(0.2 * occ_loss + 1.0 * off_loss + 1.0 * feat_loss);
    }
}

extern "C" void kernel_launch(void* const* d_in, const int* in_sizes, int n_in,
                              void* d_out, int out_size, void* d_ws, size_t ws_size,
                              hipStream_t stream) {
    const float4* pf = (const float4*)d_in[0];   // (Nr,4)
    const float*  oc = (const float*)d_in[1];    // (Nr,1,1)
    const int4*   ri = (const int4*)d_in[2];     // (Nr,4)
    const float*  lf = (const float*)d_in[3];    // (Nl,4)
    const int4*   li = (const int4*)d_in[4];     // (Nl,4)
    const int*    Rp = (const int*)d_in[5];      // scalar (device)

    const int Nr = in_sizes[0] / 4;
    const int Nl = in_sizes[3] / 4;
    const int nblkL = (Nl + BLOCK - 1) / BLOCK;          // 4096
    int nblk = (Nr + BLOCK - 1) / BLOCK;                 // 1024
    if (nblk > 2048) nblk = 2048;                        // grid-stride beyond

    // Workspace layout: [bm][stab][counter] is one contiguous zero region.
    size_t off = 0;
    auto alloc = [&](size_t n) { size_t o = off; off += (n + 255) & ~(size_t)255; return o; };
    char* ws = (char*)d_ws;
    unsigned*           bm    = (unsigned*)(ws + alloc(BM_BYTES));
    unsigned long long* stab  = (unsigned long long*)(ws + alloc(STAB_BYTES));
    unsigned*           counter = (unsigned*)(ws + alloc(256));
    const size_t zeroBytes = off;                        // bm + stab + counter
    unsigned*           cells = (unsigned*)(ws + alloc((size_t)Nl * 4));
    int*                mcell = (int*)(ws + alloc((size_t)Nr * 4));
    double*             parts = (double*)(ws + alloc((size_t)nblk * 4 * sizeof(double)));
    double*             fpart = (double*)(ws + alloc((size_t)nblk * sizeof(double)));

    k_clear<<<2048, BLOCK, 0, stream>>>((uint2*)ws, (int)(zeroBytes / 8));
    k_build<<<nblkL, BLOCK, 0, stream>>>(li, Nl, bm, cells);
    k_match<<<nblk, BLOCK, 0, stream>>>(pf, oc, ri, bm, stab, Rp, Nr, mcell, parts);
    k_scan<<<nblkL, BLOCK, 0, stream>>>(cells, Nl, stab);
    k_feat<<<nblk, BLOCK, 0, stream>>>((const float*)pf, mcell, stab, lf, Nr, fpart,
                                       parts, counter, nblk, (float*)d_out);
}